// Round 5
// baseline (38.934 us; speedup 1.0000x reference)
//
#include <hip/hip_runtime.h>
#include <hip/hip_fp16.h>
#include <hip/hip_bf16.h>

#define NN 256
#define AA 1024
#define BBB 128
#define CCC 32
#define JJ 4096          // B*C
#define OUTW 1152        // A + B

typedef __attribute__((ext_vector_type(8))) short short8v;
typedef __attribute__((ext_vector_type(4))) float floatx4;

__device__ __forceinline__ unsigned f2bf(float f) {
    __hip_bfloat16 h = __float2bfloat16(f);   // RNE hardware convert
    return (unsigned)*(unsigned short*)&h;
}

// ---------------------------------------------------------------------------
// cvt_copy: out[n][0:1024] = x[n][:]  AND  xb = bf16(x)  (one read of x).
// ---------------------------------------------------------------------------
__global__ __launch_bounds__(256) void cvt_copy(const float* __restrict__ x,
                                                float* __restrict__ out,
                                                unsigned short* __restrict__ xb) {
    const int row = blockIdx.x;
    const int t = threadIdx.x;
    float4 v = *(const float4*)&x[(size_t)row * AA + t * 4];
    *(float4*)&out[(size_t)row * OUTW + t * 4] = v;
    uint2 p;
    p.x = f2bf(v.x) | (f2bf(v.y) << 16);
    p.y = f2bf(v.z) | (f2bf(v.w) << 16);
    *(uint2*)&xb[(size_t)row * AA + t * 4] = p;
}

// ---------------------------------------------------------------------------
// fused: per block (b = bid&127, h = bid>>7):
//   phase 1: M_b[256][32] = x @ T[:, b*32 .. b*32+32)   (bf16 MFMA, f32 acc)
//   phase 2: o[n][b] = sum_m exp(-sum_c |M_b[n][c]-M_b[m][c]|)  for n in h-half
// 512 threads (8 waves). GEMM: 16 k-chunks of KC=64, reg-prefetch 1 ahead,
// single-buffered LDS (2 barriers/chunk). Wave w owns rows 32w..32w+31
// (2 MFMA row-tiles), both 16-col j-tiles -> 8 ds_read + 8 MFMA per chunk.
// LDS tiles [row][64 k] bf16 = 128 B rows, XOR swizzle byte ^= ((row&7)<<4)
// on write AND read (rule 21; swizzle bits 4-6, kbyte range 0..127).
// The b/h block mapping puts the two blocks sharing a T-slice on one XCD
// (ids b and b+128 are congruent mod 8) -> slice fetched once into that L2.
// ---------------------------------------------------------------------------
__global__ __launch_bounds__(512) void fused(const unsigned short* __restrict__ xb,
                                             const float* __restrict__ T,
                                             float* __restrict__ out) {
    __shared__ unsigned short xs[256 * 64];   // 32 KB, swizzled [n][k]
    __shared__ unsigned short ts[32 * 64];    // 4 KB,  swizzled [j][k]
    __shared__ __half Mb[256][32];            // 16 KB
    __shared__ float red[3][128];

    const int bid = blockIdx.x;
    const int b = bid & 127;
    const int h = bid >> 7;
    const int tid = threadIdx.x;
    const int lane = tid & 63;
    const int w = tid >> 6;

    // ---- staging assignments ----
    const int xr0 = tid >> 3;                 // x row 0..63 (+64p)
    const int xkq = (tid & 7) * 8;            // x k elem offset
    const unsigned short* xp = xb + (size_t)xr0 * AA + xkq;
    const int xw = xr0 * 128 + ((xkq * 2) ^ ((xr0 & 7) << 4));   // +p*8192

    const int tc = tid & 31;                  // T col 0..31
    const int tkb = (tid >> 5) * 4;           // T k elem base 0..60
    const float* tp = T + (size_t)tkb * JJ + b * CCC + tc;
    const int tw0 = tc * 128 + (((tkb * 2)) ^ ((tc & 7) << 4));
    const int tw1 = tc * 128 + (((tkb * 2) + 4) ^ ((tc & 7) << 4));

    // ---- compute assignments ----
    const int rf = lane & 15;
    const int g = lane >> 4;
    const int swz = (rf & 7) << 4;
    const int aRd0 = (32 * w + rf) * 128 + ((16 * g) ^ swz);        // ks=0
    const int aRd1 = (32 * w + rf) * 128 + ((64 + 16 * g) ^ swz);   // ks=1
    const int bRd0 = rf * 128 + ((16 * g) ^ swz);
    const int bRd1 = rf * 128 + ((64 + 16 * g) ^ swz);

    floatx4 acc00 = {0.f, 0.f, 0.f, 0.f};
    floatx4 acc01 = {0.f, 0.f, 0.f, 0.f};
    floatx4 acc10 = {0.f, 0.f, 0.f, 0.f};
    floatx4 acc11 = {0.f, 0.f, 0.f, 0.f};

    // ---- prefetch chunk 0 into registers ----
    uint4 xv0 = *(const uint4*)(xp);
    uint4 xv1 = *(const uint4*)(xp + 64 * AA);
    uint4 xv2 = *(const uint4*)(xp + 128 * AA);
    uint4 xv3 = *(const uint4*)(xp + 192 * AA);
    float t0 = tp[0], t1 = tp[JJ], t2 = tp[2 * JJ], t3 = tp[3 * JJ];

    for (int c = 0; c < 16; ++c) {
        __syncthreads();   // all waves done computing chunk c-1 -> LDS reusable
        *(uint4*)((char*)xs + xw) = xv0;
        *(uint4*)((char*)xs + xw + 8192) = xv1;
        *(uint4*)((char*)xs + xw + 16384) = xv2;
        *(uint4*)((char*)xs + xw + 24576) = xv3;
        unsigned p0 = f2bf(t0) | (f2bf(t1) << 16);
        unsigned p1 = f2bf(t2) | (f2bf(t3) << 16);
        *(unsigned*)((char*)ts + tw0) = p0;
        *(unsigned*)((char*)ts + tw1) = p1;
        if (c < 15) {   // issue next-chunk loads (latency hides under compute)
            const unsigned short* xq = xp + (c + 1) * 64;
            xv0 = *(const uint4*)(xq);
            xv1 = *(const uint4*)(xq + 64 * AA);
            xv2 = *(const uint4*)(xq + 128 * AA);
            xv3 = *(const uint4*)(xq + 192 * AA);
            const float* tq = tp + (size_t)(c + 1) * 64 * JJ;
            t0 = tq[0]; t1 = tq[JJ]; t2 = tq[2 * JJ]; t3 = tq[3 * JJ];
        }
        __syncthreads();   // staged data visible

        // ks = 0
        short8v a0 = *(const short8v*)((char*)xs + aRd0);
        short8v a1 = *(const short8v*)((char*)xs + aRd0 + 2048);
        short8v b0 = *(const short8v*)((char*)ts + bRd0);
        short8v b1 = *(const short8v*)((char*)ts + bRd0 + 2048);
        acc00 = __builtin_amdgcn_mfma_f32_16x16x32_bf16(a0, b0, acc00, 0, 0, 0);
        acc01 = __builtin_amdgcn_mfma_f32_16x16x32_bf16(a0, b1, acc01, 0, 0, 0);
        acc10 = __builtin_amdgcn_mfma_f32_16x16x32_bf16(a1, b0, acc10, 0, 0, 0);
        acc11 = __builtin_amdgcn_mfma_f32_16x16x32_bf16(a1, b1, acc11, 0, 0, 0);
        // ks = 1
        a0 = *(const short8v*)((char*)xs + aRd1);
        a1 = *(const short8v*)((char*)xs + aRd1 + 2048);
        b0 = *(const short8v*)((char*)ts + bRd1);
        b1 = *(const short8v*)((char*)ts + bRd1 + 2048);
        acc00 = __builtin_amdgcn_mfma_f32_16x16x32_bf16(a0, b0, acc00, 0, 0, 0);
        acc01 = __builtin_amdgcn_mfma_f32_16x16x32_bf16(a0, b1, acc01, 0, 0, 0);
        acc10 = __builtin_amdgcn_mfma_f32_16x16x32_bf16(a1, b0, acc10, 0, 0, 0);
        acc11 = __builtin_amdgcn_mfma_f32_16x16x32_bf16(a1, b1, acc11, 0, 0, 0);
    }

    // ---- M_b -> LDS (C/D layout: col = lane&15, row = (lane>>4)*4 + r) ----
    const int mrow = 32 * w + (lane >> 4) * 4;
#pragma unroll
    for (int r = 0; r < 4; ++r) {
        Mb[mrow + r][rf] = __float2half(acc00[r]);
        Mb[mrow + r][rf + 16] = __float2half(acc01[r]);
        Mb[mrow + 16 + r][rf] = __float2half(acc10[r]);
        Mb[mrow + 16 + r][rf + 16] = __float2half(acc11[r]);
    }
    __syncthreads();

    // ---- pairwise: 128 n x 4 m-quarters ----
    const int nl = tid & 127;
    const int mq = tid >> 7;
    const int n = h * 128 + nl;

    union { uint4 u; __half2 hh[4]; } mv0, mv1, mv2, mv3;
    mv0.u = *(const uint4*)&Mb[n][0];
    mv1.u = *(const uint4*)&Mb[n][8];
    mv2.u = *(const uint4*)&Mb[n][16];
    mv3.u = *(const uint4*)&Mb[n][24];

    float o = 0.f;
    const int m0 = mq * 64;
    for (int m = m0; m < m0 + 64; ++m) {
        union { uint4 u; __half2 hh[4]; } rv0, rv1, rv2, rv3;
        rv0.u = *(const uint4*)&Mb[m][0];
        rv1.u = *(const uint4*)&Mb[m][8];
        rv2.u = *(const uint4*)&Mb[m][16];
        rv3.u = *(const uint4*)&Mb[m][24];
        __half2 a0 = __habs2(__hsub2(mv0.hh[0], rv0.hh[0]));
        __half2 a1 = __habs2(__hsub2(mv0.hh[1], rv0.hh[1]));
        __half2 a2 = __habs2(__hsub2(mv0.hh[2], rv0.hh[2]));
        __half2 a3 = __habs2(__hsub2(mv0.hh[3], rv0.hh[3]));
        a0 = __hadd2(a0, __habs2(__hsub2(mv1.hh[0], rv1.hh[0])));
        a1 = __hadd2(a1, __habs2(__hsub2(mv1.hh[1], rv1.hh[1])));
        a2 = __hadd2(a2, __habs2(__hsub2(mv1.hh[2], rv1.hh[2])));
        a3 = __hadd2(a3, __habs2(__hsub2(mv1.hh[3], rv1.hh[3])));
        a0 = __hadd2(a0, __habs2(__hsub2(mv2.hh[0], rv2.hh[0])));
        a1 = __hadd2(a1, __habs2(__hsub2(mv2.hh[1], rv2.hh[1])));
        a2 = __hadd2(a2, __habs2(__hsub2(mv2.hh[2], rv2.hh[2])));
        a3 = __hadd2(a3, __habs2(__hsub2(mv2.hh[3], rv2.hh[3])));
        a0 = __hadd2(a0, __habs2(__hsub2(mv3.hh[0], rv3.hh[0])));
        a1 = __hadd2(a1, __habs2(__hsub2(mv3.hh[1], rv3.hh[1])));
        a2 = __hadd2(a2, __habs2(__hsub2(mv3.hh[2], rv3.hh[2])));
        a3 = __hadd2(a3, __habs2(__hsub2(mv3.hh[3], rv3.hh[3])));
        __half2 s = __hadd2(__hadd2(a0, a1), __hadd2(a2, a3));
        float2 lf = __half22float2(s);
        o += __expf(-(lf.x + lf.y));
    }

    if (mq) red[mq - 1][nl] = o;
    __syncthreads();
    if (mq == 0) {
        o += red[0][nl] + red[1][nl] + red[2][nl];
        out[(size_t)n * OUTW + AA + b] = o;
    }
}

// ===========================================================================
extern "C" void kernel_launch(void* const* d_in, const int* in_sizes, int n_in,
                              void* d_out, int out_size, void* d_ws, size_t ws_size,
                              hipStream_t stream) {
    const float* x = (const float*)d_in[0];
    const float* T = (const float*)d_in[1];
    float* out = (float*)d_out;
    unsigned short* xbf = (unsigned short*)d_ws;   // 256*1024*2 = 512 KB

    cvt_copy<<<NN, 256, 0, stream>>>(x, out, xbf);
    fused<<<256, 512, 0, stream>>>(xbf, T, out);
}

// Round 6
// 37.480 us; speedup vs baseline: 1.0388x; 1.0388x over previous
//
#include <hip/hip_runtime.h>
#include <hip/hip_fp16.h>
#include <hip/hip_bf16.h>

#define NN 256
#define AA 1024
#define JJ 4096          // B*C
#define OUTW 1152        // A + B

typedef __attribute__((ext_vector_type(8))) short short8v;
typedef __attribute__((ext_vector_type(4))) float floatx4;

__device__ __forceinline__ unsigned f2bf(float f) {
    __hip_bfloat16 h = __float2bfloat16(f);   // RNE hardware convert
    return (unsigned)*(unsigned short*)&h;
}

// ---------------------------------------------------------------------------
// copy_x: out[n][0:1024] = x[n][:]   (independent of gemm -> runs parallel)
// ---------------------------------------------------------------------------
__global__ __launch_bounds__(256) void copy_x(const float* __restrict__ x,
                                              float* __restrict__ out) {
    const int n = blockIdx.x;
    const int t = threadIdx.x;
    *(float4*)&out[(size_t)n * OUTW + t * 4] =
        *(const float4*)&x[(size_t)n * AA + t * 4];
}

// ---------------------------------------------------------------------------
// gemm: M[n][j] = sum_k x[n][k]*T[k][j]; f32 in, bf16 MFMA 16x16x32, f16 out.
// Tile 32n x 64j, TK=64. Grid (64 j, 8 n) = 512 blocks (2/CU), 256 thr (4 w).
// Wave w: nh=w&1 -> rows nh*16..+16; jh=w>>1 -> cols jh*32..+32 (2 frags).
// Per chunk/wave: 6 ds_read_b128 + 4 MFMA. Double-buffered LDS, ONE barrier
// per chunk: [stage c -> buf[c&1] (regs from last iter's prefetch), issue
// prefetch c+1, barrier, compute c]. Stage(c) writes buf[c&1], last read by
// compute(c-2) before iter (c-1)'s barrier -> race-free.
// LDS layout [row][64k] bf16 (128B rows), XOR swizzle byte^=((row&7)<<4)
// identically on write and read (rule 21; swizzle bits 4-6 stay in-row).
// T-slice sharing: blocks with equal blockIdx.x are bid%8-congruent -> same
// XCD L2 gets each T j-slice.
// ---------------------------------------------------------------------------
__global__ __launch_bounds__(256) void gemm(const float* __restrict__ x,
                                            const float* __restrict__ T,
                                            __half* __restrict__ Mh) {
    __shared__ unsigned short xs[2][32 * 64];   // 4 KB each
    __shared__ unsigned short ts[2][64 * 64];   // 8 KB each

    const int tid = threadIdx.x;
    const int lane = tid & 63;
    const int w = tid >> 6;
    const int col0 = blockIdx.x * 64;
    const int row0 = blockIdx.y * 32;

    // A staging: 1 row x 8 k per thread (f32 -> bf16)
    const int xr = tid >> 3;                  // 0..31
    const int xk = (tid & 7) * 8;
    const float* xp = x + (size_t)(row0 + xr) * AA + xk;
    const int xW = xr * 128 + ((xk * 2) ^ ((xr & 7) << 4));

    // B staging: 4 j x 4 k per thread (transpose + convert)
    const int tj = (tid & 15) * 4;
    const int tk = (tid >> 4) * 4;
    const float* tp = T + (size_t)tk * JJ + col0 + tj;
    int tWr[4];
#pragma unroll
    for (int q = 0; q < 4; ++q) {
        const int row = tj + q;
        tWr[q] = row * 128 + ((tk * 2) ^ ((row & 7) << 4));
    }

    // compute assignments
    const int rf = lane & 15;
    const int g = lane >> 4;
    const int nh = w & 1;
    const int jh = w >> 1;
    const int swz = (rf & 7) << 4;
    const int aBase = (nh * 16 + rf) * 128;
    const int b0Base = (jh * 32 + rf) * 128;
    const int b1Base = (jh * 32 + 16 + rf) * 128;
    const int k0off = (g * 16) ^ swz;          // ks=0
    const int k1off = (64 + g * 16) ^ swz;     // ks=1

    floatx4 acc0 = {0.f, 0.f, 0.f, 0.f};
    floatx4 acc1 = {0.f, 0.f, 0.f, 0.f};

    // prologue: prefetch chunk 0
    float4 xa = *(const float4*)(xp);
    float4 xb2 = *(const float4*)(xp + 4);
    float4 t0 = *(const float4*)(tp);
    float4 t1 = *(const float4*)(tp + JJ);
    float4 t2 = *(const float4*)(tp + 2 * JJ);
    float4 t3 = *(const float4*)(tp + 3 * JJ);

    for (int c = 0; c < 16; ++c) {
        const int cur = c & 1;
        // ---- stage chunk c ----
        {
            uint4 pa;
            pa.x = f2bf(xa.x) | (f2bf(xa.y) << 16);
            pa.y = f2bf(xa.z) | (f2bf(xa.w) << 16);
            pa.z = f2bf(xb2.x) | (f2bf(xb2.y) << 16);
            pa.w = f2bf(xb2.z) | (f2bf(xb2.w) << 16);
            *(uint4*)((char*)xs[cur] + xW) = pa;
            uint2 p;
            p.x = f2bf(t0.x) | (f2bf(t1.x) << 16);
            p.y = f2bf(t2.x) | (f2bf(t3.x) << 16);
            *(uint2*)((char*)ts[cur] + tWr[0]) = p;
            p.x = f2bf(t0.y) | (f2bf(t1.y) << 16);
            p.y = f2bf(t2.y) | (f2bf(t3.y) << 16);
            *(uint2*)((char*)ts[cur] + tWr[1]) = p;
            p.x = f2bf(t0.z) | (f2bf(t1.z) << 16);
            p.y = f2bf(t2.z) | (f2bf(t3.z) << 16);
            *(uint2*)((char*)ts[cur] + tWr[2]) = p;
            p.x = f2bf(t0.w) | (f2bf(t1.w) << 16);
            p.y = f2bf(t2.w) | (f2bf(t3.w) << 16);
            *(uint2*)((char*)ts[cur] + tWr[3]) = p;
        }
        // ---- issue prefetch for chunk c+1 ----
        if (c < 15) {
            const float* xq = xp + (c + 1) * 64;
            xa = *(const float4*)(xq);
            xb2 = *(const float4*)(xq + 4);
            const float* tq = tp + (size_t)(c + 1) * 64 * JJ;
            t0 = *(const float4*)(tq);
            t1 = *(const float4*)(tq + JJ);
            t2 = *(const float4*)(tq + 2 * JJ);
            t3 = *(const float4*)(tq + 3 * JJ);
        }
        __syncthreads();
        // ---- compute chunk c from buf[cur] ----
        short8v a0 = *(const short8v*)((char*)xs[cur] + aBase + k0off);
        short8v b00 = *(const short8v*)((char*)ts[cur] + b0Base + k0off);
        short8v b10 = *(const short8v*)((char*)ts[cur] + b1Base + k0off);
        acc0 = __builtin_amdgcn_mfma_f32_16x16x32_bf16(a0, b00, acc0, 0, 0, 0);
        acc1 = __builtin_amdgcn_mfma_f32_16x16x32_bf16(a0, b10, acc1, 0, 0, 0);
        short8v a1 = *(const short8v*)((char*)xs[cur] + aBase + k1off);
        short8v b01 = *(const short8v*)((char*)ts[cur] + b0Base + k1off);
        short8v b11 = *(const short8v*)((char*)ts[cur] + b1Base + k1off);
        acc0 = __builtin_amdgcn_mfma_f32_16x16x32_bf16(a1, b01, acc0, 0, 0, 0);
        acc1 = __builtin_amdgcn_mfma_f32_16x16x32_bf16(a1, b11, acc1, 0, 0, 0);
    }

    // C/D layout: col = lane&15, row = (lane>>4)*4 + reg
    const int colw = col0 + jh * 32 + rf;
    const int rbase = row0 + nh * 16 + g * 4;
#pragma unroll
    for (int r = 0; r < 4; ++r) {
        Mh[(size_t)(rbase + r) * JJ + colw] = __float2half(acc0[r]);
        Mh[(size_t)(rbase + r) * JJ + colw + 16] = __float2half(acc1[r]);
    }
}

// ---------------------------------------------------------------------------
// pairwise: o[n][b] = sum_m exp(-sum_c |M[n][b,c]-M[m][b,c]|), f16 packed.
// Grid 256 = (b = bid&127, h = bid>>7). 512 thr = 64 n-pairs x 8 m-chunks.
// Each thread owns 2 n rows (regs) -> per broadcast rv row, 2x arithmetic:
// halves the LDS-pipe load vs 1 n/thread (the r4 bottleneck).
// rv reads are wave-uniform (m loop, mq per-wave) -> broadcast, conflict-free.
// ---------------------------------------------------------------------------
__global__ __launch_bounds__(512) void pairwise(const __half* __restrict__ Mh,
                                                float* __restrict__ out) {
    __shared__ __half Mb[256][32];    // 16 KB
    __shared__ float red[8][128];     // 4 KB
    const int bid = blockIdx.x;
    const int b = bid & 127;
    const int h = bid >> 7;
    const int tid = threadIdx.x;

    {   // stage all 256 rows of M[:, b, :]
        const int m = tid >> 1;
        const int ch = (tid & 1) * 16;
        *(uint4*)&Mb[m][ch] = *(const uint4*)&Mh[(size_t)m * JJ + b * 32 + ch];
        *(uint4*)&Mb[m][ch + 8] =
            *(const uint4*)&Mh[(size_t)m * JJ + b * 32 + ch + 8];
    }

    const int np = (tid & 63) * 2;    // n-pair within half
    const int mq = tid >> 6;          // 0..7 (uniform per wave)
    const int n0 = h * 128 + np;

    union u4h { uint4 u; __half2 hh[4]; };
    u4h mv[2][4];
#pragma unroll
    for (int r = 0; r < 2; ++r)
#pragma unroll
        for (int i = 0; i < 4; ++i)
            mv[r][i].u = *(const uint4*)&Mh[(size_t)(n0 + r) * JJ + b * 32 + i * 8];

    __syncthreads();

    float o0 = 0.f, o1 = 0.f;
    const int m0 = mq * 32;
    for (int m = m0; m < m0 + 32; ++m) {
        u4h rv[4];
#pragma unroll
        for (int i = 0; i < 4; ++i) rv[i].u = *(const uint4*)&Mb[m][i * 8];
#pragma unroll
        for (int r = 0; r < 2; ++r) {
            __half2 a0 = __habs2(__hsub2(mv[r][0].hh[0], rv[0].hh[0]));
            __half2 a1 = __habs2(__hsub2(mv[r][0].hh[1], rv[0].hh[1]));
            __half2 a2 = __habs2(__hsub2(mv[r][0].hh[2], rv[0].hh[2]));
            __half2 a3 = __habs2(__hsub2(mv[r][0].hh[3], rv[0].hh[3]));
#pragma unroll
            for (int i = 1; i < 4; ++i) {
                a0 = __hadd2(a0, __habs2(__hsub2(mv[r][i].hh[0], rv[i].hh[0])));
                a1 = __hadd2(a1, __habs2(__hsub2(mv[r][i].hh[1], rv[i].hh[1])));
                a2 = __hadd2(a2, __habs2(__hsub2(mv[r][i].hh[2], rv[i].hh[2])));
                a3 = __hadd2(a3, __habs2(__hsub2(mv[r][i].hh[3], rv[i].hh[3])));
            }
            __half2 s = __hadd2(__hadd2(a0, a1), __hadd2(a2, a3));
            float2 lf = __half22float2(s);
            float e = __expf(-(lf.x + lf.y));
            if (r == 0) o0 += e; else o1 += e;
        }
    }

    *(float2*)&red[mq][np] = make_float2(o0, o1);
    __syncthreads();
    if (tid < 128) {
        float o = 0.f;
#pragma unroll
        for (int q = 0; q < 8; ++q) o += red[q][tid];
        out[(size_t)(h * 128 + tid) * OUTW + AA + b] = o;
    }
}

// ===========================================================================
extern "C" void kernel_launch(void* const* d_in, const int* in_sizes, int n_in,
                              void* d_out, int out_size, void* d_ws, size_t ws_size,
                              hipStream_t stream) {
    const float* x = (const float*)d_in[0];
    const float* T = (const float*)d_in[1];
    float* out = (float*)d_out;
    __half* Mh = (__half*)d_ws;               // 256*4096*2 = 2 MB

    gemm<<<dim3(64, 8), 256, 0, stream>>>(x, T, Mh);
    copy_x<<<NN, 256, 0, stream>>>(x, out);
    pairwise<<<256, 512, 0, stream>>>(Mh, out);
}